// Round 1
// 449.633 us; speedup vs baseline: 1.0227x; 1.0227x over previous
//
#include <hip/hip_runtime.h>
#include <math.h>

#define NT 8192
#define NO 8192
#define FIN 256
#define FOUT 64
#define SPLIT 8
#define JSP (NO/SPLIT)  // 1024 j per split
#define ROWT 64         // rows per attention block (4 waves x 16 rows)

// workspace layout (float offsets)
#define OFF_ST  ((size_t)0)                           // 8192
#define OFF_SO  (OFF_ST + (size_t)NT)                 // 8192
#define OFF_WT  (OFF_SO + (size_t)NO)                 // 256
#define OFF_WO  (OFF_WT + (size_t)FIN)                // 256
#define OFF_NUM (OFF_WO + (size_t)FIN)                // SPLIT*8192*64
#define OFF_DEN (OFF_NUM + (size_t)SPLIT*NT*FOUT)     // SPLIT*8192
#define OFF_HOB (OFF_DEN + (size_t)SPLIT*NT)          // NO*FOUT bf16 (B-frag order)
#define OFF_ETA (OFF_HOB + (size_t)NO*FOUT/2)         // NO*2 floats (eso, eso2)
// total ~= 4.6M floats ~= 18 MB of d_ws

typedef __attribute__((ext_vector_type(8))) short short8;
typedef __attribute__((ext_vector_type(4))) float float4v;

static __device__ __forceinline__ unsigned short f2bf(float x) {
  unsigned int u = __float_as_uint(x);
  unsigned int r = (u + 0x7fffu + ((u >> 16) & 1u)) >> 16;   // RNE
  return (unsigned short)r;
}
static __device__ __forceinline__ int pk2(float a, float b) {
  return (int)((unsigned int)f2bf(a) | ((unsigned int)f2bf(b) << 16));
}
static __device__ __forceinline__ float bflo(int p) {
  return __uint_as_float(((unsigned int)p) << 16);
}
static __device__ __forceinline__ float bfhi(int p) {
  return __uint_as_float(((unsigned int)p) & 0xffff0000u);
}

// K1: fold wt = W_t @ a_t, wo = W_o @ a_o  (256-vectors)
__global__ void k_wvec(const float* __restrict__ Wt, const float* __restrict__ Wo,
                       const float* __restrict__ a, float* __restrict__ ws) {
  int k = threadIdx.x;  // 0..255
  float s1 = 0.f, s2 = 0.f;
#pragma unroll
  for (int fq = 0; fq < FOUT/4; ++fq) {
    float4 wt4 = *(const float4*)(Wt + (size_t)k*FOUT + fq*4);
    float4 wo4 = *(const float4*)(Wo + (size_t)k*FOUT + fq*4);
    float4 at4 = *(const float4*)(a + fq*4);
    float4 ao4 = *(const float4*)(a + FOUT + fq*4);
    s1 += wt4.x*at4.x + wt4.y*at4.y + wt4.z*at4.z + wt4.w*at4.w;
    s2 += wo4.x*ao4.x + wo4.y*ao4.y + wo4.z*ao4.z + wo4.w*ao4.w;
  }
  ws[OFF_WT + k] = s1;
  ws[OFF_WO + k] = s2;
}

// K2: s_t = t_input @ wt   (wave per row)
__global__ void k_st(const float* __restrict__ tin, float* __restrict__ ws) {
  int lane = threadIdx.x & 63;
  int wv   = threadIdx.x >> 6;
  int row  = blockIdx.x * 4 + wv;
  float4 v = ((const float4*)(tin + (size_t)row*FIN))[lane];
  float4 w = ((const float4*)(ws + OFF_WT))[lane];
  float p = v.x*w.x + v.y*w.y + v.z*w.z + v.w*w.w;
#pragma unroll
  for (int m = 32; m >= 1; m >>= 1) p += __shfl_xor(p, m, 64);
  if (lane == 0) ws[OFF_ST + row] = p;
}

// K3: h_o = o_input @ W_o (fp32). Outputs: hobp bf16 in EXACT B-fragment
// order (tile jt, fg, lane, e) so k_attn's B loads are coalesced 16B/lane;
// and s_o (fp32). 4 rows per wave, 512 blocks (2/CU).
__global__ void k_ho(const float* __restrict__ oin, const float* __restrict__ Wo,
                     const float* __restrict__ a, float* __restrict__ ws) {
  unsigned short* hobp = (unsigned short*)(ws + OFF_HOB);
  int lane = threadIdx.x & 63;
  int wv = __builtin_amdgcn_readfirstlane(threadIdx.x >> 6);
  int r0 = blockIdx.x * 16 + wv * 4;
  const float* ob = oin + (size_t)r0 * FIN;
  float acc[4];
#pragma unroll
  for (int r = 0; r < 4; ++r) acc[r] = 0.f;
#pragma unroll 2
  for (int k = 0; k < FIN; k += 4) {
    float w0 = Wo[(size_t)(k+0)*FOUT + lane];
    float w1 = Wo[(size_t)(k+1)*FOUT + lane];
    float w2 = Wo[(size_t)(k+2)*FOUT + lane];
    float w3 = Wo[(size_t)(k+3)*FOUT + lane];
#pragma unroll
    for (int r = 0; r < 4; ++r) {
      float4 ov = *(const float4*)(ob + (size_t)r*FIN + k);
      acc[r] = fmaf(ov.x, w0, acc[r]);
      acc[r] = fmaf(ov.y, w1, acc[r]);
      acc[r] = fmaf(ov.z, w2, acc[r]);
      acc[r] = fmaf(ov.w, w3, acc[r]);
    }
  }
  float ao = a[FOUT + lane];
  int fg = lane >> 4, n16 = lane & 15;
#pragma unroll
  for (int r = 0; r < 4; ++r) {
    int j = r0 + r;
    int jt = j >> 5, jl = j & 31;
    int ldst = (jl >> 3) * 16 + n16;      // consumer lane
    int e = jl & 7;
    hobp[(((size_t)jt*4 + fg)*64 + ldst)*8 + e] = f2bf(acc[r]);
    float p = acc[r] * ao;
#pragma unroll
    for (int m = 32; m >= 1; m >>= 1) p += __shfl_xor(p, m, 64);
    if (lane == 0) ws[OFF_SO + j] = p;
  }
}

// K4: exp tables: etab[2j] = exp(s_o[j]), etab[2j+1] = exp(0.2*s_o[j]).
__global__ void k_etab(float* __restrict__ ws) {
  int j = blockIdx.x * 256 + threadIdx.x;
  float s = ws[OFF_SO + j];
  ws[OFF_ETA + 2*j + 0] = __expf(s);
  ws[OFF_ETA + 2*j + 1] = __expf(0.2f * s);
}

// K5: fused masked-softmax attention. Zero LDS/barriers. The 268 MB int32
// adjacency is streamed DIRECTLY in this kernel (k_mask pass deleted): each
// element is consumed exactly once, so the stream overlaps with the
// VALU/bpermute/MFMA work instead of costing a separate bandwidth-only pass.
// Distance-1 software prefetch keeps 2 adjacency loads in flight per wave.
// No exp in loop: w = exp(leaky(st+so)) = (so >= -st) ? exp(st)exp(so)
//                                                     : exp(.2st)exp(.2so),
// branch via monotone compare eso >= exp(-st). den from bf16-rounded w.
// A-frag in registers: lane l = row l&15, k-cols (l>>4)*8..+8 (source map
// row l>>2 / chunk l&3 then 4x ds_bpermute after packing).
__launch_bounds__(256, 4)
__global__ void k_attn(const int* __restrict__ adj, float* __restrict__ ws) {
  const float* st = ws + OFF_ST;
  const float* etab = ws + OFF_ETA;
  const unsigned short* hobp = (const unsigned short*)(ws + OFF_HOB);
  float* gnum = ws + OFF_NUM;
  float* gden = ws + OFF_DEN;

  int t = threadIdx.x;
  int wv = t >> 6, lane = t & 63;
  int bx = blockIdx.x;
  int s  = bx & (SPLIT - 1);
  int bi = bx >> 3;                 // log2(SPLIT)
  int i0 = bi * ROWT;
  int jb = s * JSP;

  // source-lane mapping (coalesced loads): row rsrc = lane>>2, chunk csrc = lane&3
  int rsrc = lane >> 2, csrc = lane & 3;
  int irow_s = i0 + wv*16 + rsrc;
  float sti  = st[irow_s];
  float esti  = __expf(sti);
  float esti2 = __expf(0.2f * sti);
  float ethr  = __expf(-sti);

  // adjacency: lane covers j = jb + csrc*8 + tt*32 + e, e=0..7 (2x int4)
  const int* arow = adj + (size_t)irow_s * NO + jb + csrc*8;
  const float* ep = etab + (size_t)(jb + csrc*8) * 2;
  const unsigned short* hpb = hobp + (size_t)(jb >> 5) * 2048 + lane*8;

  // target-lane A-frag mapping + bpermute source index
  int r16 = lane & 15, kg = lane >> 4;
  int sidx4 = ((r16 * 4 + kg) << 2);

  float4v acc0 = (float4v)0.f, acc1 = (float4v)0.f;
  float4v acc2 = (float4v)0.f, acc3 = (float4v)0.f;
  float dsum = 0.f;

  int4 a0 = *(const int4*)(arow);
  int4 a1 = *(const int4*)(arow + 4);

#pragma unroll 1
  for (int tt = 0; tt < JSP/32; ++tt) {
    // distance-1 prefetch of next tt's adjacency (clamped: last iter re-loads)
    int ttn = (tt < JSP/32 - 1) ? tt + 1 : tt;
    int4 n0 = *(const int4*)(arow + ttn*32);
    int4 n1 = *(const int4*)(arow + ttn*32 + 4);

    const float* e_ = ep + tt*64;
    float4 e0 = *(const float4*)(e_);        // (eso,eso2) cols +0,+1
    float4 e1 = *(const float4*)(e_ + 4);    // +2,+3
    float4 e2 = *(const float4*)(e_ + 8);    // +4,+5
    float4 e3 = *(const float4*)(e_ + 12);   // +6,+7
    const unsigned short* hb = hpb + (size_t)tt*2048;
    short8 b0 = *(const short8*)(hb);
    short8 b1 = *(const short8*)(hb + 512);
    short8 b2 = *(const short8*)(hb + 1024);
    short8 b3 = *(const short8*)(hb + 1536);

    float w0 = ((e0.x >= ethr) ? esti*e0.x : esti2*e0.y); w0 = (a0.x > 0) ? w0 : 0.f;
    float w1 = ((e0.z >= ethr) ? esti*e0.z : esti2*e0.w); w1 = (a0.y > 0) ? w1 : 0.f;
    float w2 = ((e1.x >= ethr) ? esti*e1.x : esti2*e1.y); w2 = (a0.z > 0) ? w2 : 0.f;
    float w3 = ((e1.z >= ethr) ? esti*e1.z : esti2*e1.w); w3 = (a0.w > 0) ? w3 : 0.f;
    float w4 = ((e2.x >= ethr) ? esti*e2.x : esti2*e2.y); w4 = (a1.x > 0) ? w4 : 0.f;
    float w5 = ((e2.z >= ethr) ? esti*e2.z : esti2*e2.w); w5 = (a1.y > 0) ? w5 : 0.f;
    float w6 = ((e3.x >= ethr) ? esti*e3.x : esti2*e3.y); w6 = (a1.z > 0) ? w6 : 0.f;
    float w7 = ((e3.z >= ethr) ? esti*e3.z : esti2*e3.w); w7 = (a1.w > 0) ? w7 : 0.f;

    int p0 = pk2(w0, w1);
    int p1 = pk2(w2, w3);
    int p2 = pk2(w4, w5);
    int p3 = pk2(w6, w7);
    dsum += bflo(p0) + bfhi(p0) + bflo(p1) + bfhi(p1)
          + bflo(p2) + bfhi(p2) + bflo(p3) + bfhi(p3);

    int4 ai;
    ai.x = __builtin_amdgcn_ds_bpermute(sidx4, p0);
    ai.y = __builtin_amdgcn_ds_bpermute(sidx4, p1);
    ai.z = __builtin_amdgcn_ds_bpermute(sidx4, p2);
    ai.w = __builtin_amdgcn_ds_bpermute(sidx4, p3);
    short8 afrag = *(short8*)&ai;

    acc0 = __builtin_amdgcn_mfma_f32_16x16x32_bf16(afrag, b0, acc0, 0, 0, 0);
    acc1 = __builtin_amdgcn_mfma_f32_16x16x32_bf16(afrag, b1, acc1, 0, 0, 0);
    acc2 = __builtin_amdgcn_mfma_f32_16x16x32_bf16(afrag, b2, acc2, 0, 0, 0);
    acc3 = __builtin_amdgcn_mfma_f32_16x16x32_bf16(afrag, b3, acc3, 0, 0, 0);

    a0 = n0; a1 = n1;
  }

  // den: dsum is per (row rsrc, chunk csrc) — reduce over the 4 chunks
  dsum += __shfl_xor(dsum, 1, 64);
  dsum += __shfl_xor(dsum, 2, 64);
  if (csrc == 0) gden[(size_t)s*NT + i0 + wv*16 + rsrc] = dsum;

  // num partials: C/D layout col=lane&15, row=(lane>>4)*4+reg
  size_t obase = ((size_t)s*NT + i0 + wv*16 + kg*4) * FOUT + r16;
#pragma unroll
  for (int r = 0; r < 4; ++r) {
    gnum[obase + (size_t)r*FOUT +  0] = acc0[r];
    gnum[obase + (size_t)r*FOUT + 16] = acc1[r];
    gnum[obase + (size_t)r*FOUT + 32] = acc2[r];
    gnum[obase + (size_t)r*FOUT + 48] = acc3[r];
  }
}

// K6: combine splits, normalize, ELU
__global__ void k_comb(const float* __restrict__ ws, float* __restrict__ out) {
  int idx = blockIdx.x * 256 + threadIdx.x;   // 0..524287
  int i = idx >> 6;
  float num = 0.f, den = 0.f;
#pragma unroll
  for (int s = 0; s < SPLIT; ++s) {
    num += ws[OFF_NUM + ((size_t)s*NT + i)*FOUT + (idx & 63)];
    den += ws[OFF_DEN + (size_t)s*NT + i];
  }
  float r = num / den;
  out[idx] = (r > 0.f) ? r : (__expf(r) - 1.f);
}

extern "C" void kernel_launch(void* const* d_in, const int* in_sizes, int n_in,
                              void* d_out, int out_size, void* d_ws, size_t ws_size,
                              hipStream_t stream) {
  const float* tin = (const float*)d_in[0];
  const float* oin = (const float*)d_in[1];
  const float* Wt  = (const float*)d_in[2];
  const float* Wo  = (const float*)d_in[3];
  const float* a   = (const float*)d_in[4];
  const int*   adj = (const int*)d_in[5];
  float* out = (float*)d_out;
  float* ws  = (float*)d_ws;

  hipLaunchKernelGGL(k_wvec, dim3(1),              dim3(256), 0, stream, Wt, Wo, a, ws);
  hipLaunchKernelGGL(k_st,   dim3(NT/4),           dim3(256), 0, stream, tin, ws);
  hipLaunchKernelGGL(k_ho,   dim3(NO/16),          dim3(256), 0, stream, oin, Wo, a, ws);
  hipLaunchKernelGGL(k_etab, dim3(NO/256),         dim3(256), 0, stream, ws);
  hipLaunchKernelGGL(k_attn, dim3(NT/ROWT*SPLIT),  dim3(256), 0, stream, adj, ws);
  hipLaunchKernelGGL(k_comb, dim3(NT*FOUT/256),    dim3(256), 0, stream, ws, out);
}

// Round 2
// 448.875 us; speedup vs baseline: 1.0244x; 1.0017x over previous
//
#include <hip/hip_runtime.h>
#include <math.h>

#define NT 8192
#define NO 8192
#define FIN 256
#define FOUT 64
#define SPLIT 8
#define JSP (NO/SPLIT)  // 1024 j per split
#define ROWT 64         // rows per attention block (4 waves x 16 rows)

// workspace layout (float offsets)
#define OFF_ST  ((size_t)0)                           // 8192
#define OFF_SO  (OFF_ST + (size_t)NT)                 // 8192 (unused now)
#define OFF_WT  (OFF_SO + (size_t)NO)                 // 256  (unused now)
#define OFF_WO  (OFF_WT + (size_t)FIN)                // 256  (unused now)
#define OFF_NUM (OFF_WO + (size_t)FIN)                // SPLIT*8192*64
#define OFF_DEN (OFF_NUM + (size_t)SPLIT*NT*FOUT)     // SPLIT*8192
#define OFF_HOB (OFF_DEN + (size_t)SPLIT*NT)          // NO*FOUT bf16 (B-frag order)
#define OFF_ETA (OFF_HOB + (size_t)NO*FOUT/2)         // NO*2 floats (eso, eso2)
// total ~= 4.6M floats ~= 18 MB of d_ws

typedef __attribute__((ext_vector_type(8))) short short8;
typedef __attribute__((ext_vector_type(4))) float float4v;
typedef __attribute__((ext_vector_type(4))) int int4v;

static __device__ __forceinline__ unsigned short f2bf(float x) {
  unsigned int u = __float_as_uint(x);
  unsigned int r = (u + 0x7fffu + ((u >> 16) & 1u)) >> 16;   // RNE
  return (unsigned short)r;
}
static __device__ __forceinline__ int pk2(float a, float b) {
  return (int)((unsigned int)f2bf(a) | ((unsigned int)f2bf(b) << 16));
}
static __device__ __forceinline__ float bflo(int p) {
  return __uint_as_float(((unsigned int)p) << 16);
}
static __device__ __forceinline__ float bfhi(int p) {
  return __uint_as_float(((unsigned int)p) & 0xffff0000u);
}
// nontemporal (evict-first) 16B adjacency load: the 268 MB stream must not
// evict the reused hobp/etab working set from L2/L3.
static __device__ __forceinline__ int4v ntld(const int* p) {
  return __builtin_nontemporal_load((const int4v*)p);
}

// K_ST: wt = W_t @ a_t folded in via LDS (k_wvec deleted; its wo output was
// dead). 128 blocks x 64 rows. Phase 1: thread k computes wt[k] (Wt row dot
// a_t, 64 KB Wt L2-resident). Phase 2: wave per 16 rows of s_t.
__global__ void k_st(const float* __restrict__ tin, const float* __restrict__ Wt,
                     const float* __restrict__ a, float* __restrict__ ws) {
  __shared__ float wt_s[FIN];
  int k = threadIdx.x;  // 0..255
  float s1 = 0.f;
#pragma unroll
  for (int fq = 0; fq < FOUT/4; ++fq) {
    float4 wt4 = *(const float4*)(Wt + (size_t)k*FOUT + fq*4);
    float4 at4 = *(const float4*)(a + fq*4);
    s1 += wt4.x*at4.x + wt4.y*at4.y + wt4.z*at4.z + wt4.w*at4.w;
  }
  wt_s[k] = s1;
  __syncthreads();

  int lane = threadIdx.x & 63;
  int wv   = threadIdx.x >> 6;
  float4 w = ((const float4*)wt_s)[lane];
#pragma unroll
  for (int r = 0; r < 16; ++r) {
    int row = blockIdx.x * 64 + wv * 16 + r;
    float4 v = ((const float4*)(tin + (size_t)row*FIN))[lane];
    float p = v.x*w.x + v.y*w.y + v.z*w.z + v.w*w.w;
#pragma unroll
    for (int m = 32; m >= 1; m >>= 1) p += __shfl_xor(p, m, 64);
    if (lane == 0) ws[OFF_ST + row] = p;
  }
}

// K_HO: h_o = o_input @ W_o (fp32). Outputs: hobp bf16 in EXACT B-fragment
// order (tile jt, fg, lane, e) so k_attn's B loads are coalesced 16B/lane;
// and etab (k_etab folded in: lane 0 writes the exp pair directly).
__global__ void k_ho(const float* __restrict__ oin, const float* __restrict__ Wo,
                     const float* __restrict__ a, float* __restrict__ ws) {
  unsigned short* hobp = (unsigned short*)(ws + OFF_HOB);
  int lane = threadIdx.x & 63;
  int wv = __builtin_amdgcn_readfirstlane(threadIdx.x >> 6);
  int r0 = blockIdx.x * 16 + wv * 4;
  const float* ob = oin + (size_t)r0 * FIN;
  float acc[4];
#pragma unroll
  for (int r = 0; r < 4; ++r) acc[r] = 0.f;
#pragma unroll 2
  for (int k = 0; k < FIN; k += 4) {
    float w0 = Wo[(size_t)(k+0)*FOUT + lane];
    float w1 = Wo[(size_t)(k+1)*FOUT + lane];
    float w2 = Wo[(size_t)(k+2)*FOUT + lane];
    float w3 = Wo[(size_t)(k+3)*FOUT + lane];
#pragma unroll
    for (int r = 0; r < 4; ++r) {
      float4 ov = *(const float4*)(ob + (size_t)r*FIN + k);
      acc[r] = fmaf(ov.x, w0, acc[r]);
      acc[r] = fmaf(ov.y, w1, acc[r]);
      acc[r] = fmaf(ov.z, w2, acc[r]);
      acc[r] = fmaf(ov.w, w3, acc[r]);
    }
  }
  float ao = a[FOUT + lane];
  int fg = lane >> 4, n16 = lane & 15;
#pragma unroll
  for (int r = 0; r < 4; ++r) {
    int j = r0 + r;
    int jt = j >> 5, jl = j & 31;
    int ldst = (jl >> 3) * 16 + n16;      // consumer lane
    int e = jl & 7;
    hobp[(((size_t)jt*4 + fg)*64 + ldst)*8 + e] = f2bf(acc[r]);
    float p = acc[r] * ao;
#pragma unroll
    for (int m = 32; m >= 1; m >>= 1) p += __shfl_xor(p, m, 64);
    if (lane == 0) {
      ws[OFF_ETA + 2*j + 0] = __expf(p);
      ws[OFF_ETA + 2*j + 1] = __expf(0.2f * p);
    }
  }
}

// K_ATTN: fused masked-softmax attention. Zero LDS/barriers. 268 MB int32
// adjacency streamed directly with NONTEMPORAL loads (read-once; keep
// hobp/etab L2/L3-resident) and TRUE DISTANCE-2 prefetch: 2x-unrolled loop
// with statically-named double buffers so each HBM load has ~2 body-lengths
// x 4 waves/SIMD of latency cover (>> 900-cycle HBM miss).
// No exp in loop: w = exp(leaky(st+so)) = (so >= -st) ? exp(st)exp(so)
//                                                     : exp(.2st)exp(.2so),
// branch via monotone compare eso >= exp(-st). den from bf16-rounded w.
// A-frag in registers: lane l = row l&15, k-cols (l>>4)*8..+8 (source map
// row l>>2 / chunk l&3 then 4x ds_bpermute after packing).
#define ATTN_BODY(TT, A0, A1) do {                                             \
    const float* e_ = ep + (TT)*64;                                            \
    float4 e0 = *(const float4*)(e_);                                          \
    float4 e1 = *(const float4*)(e_ + 4);                                      \
    float4 e2 = *(const float4*)(e_ + 8);                                      \
    float4 e3 = *(const float4*)(e_ + 12);                                     \
    const unsigned short* hb = hpb + (size_t)(TT)*2048;                        \
    short8 b0 = *(const short8*)(hb);                                          \
    short8 b1 = *(const short8*)(hb + 512);                                    \
    short8 b2 = *(const short8*)(hb + 1024);                                   \
    short8 b3 = *(const short8*)(hb + 1536);                                   \
    float w0 = ((e0.x >= ethr) ? esti*e0.x : esti2*e0.y); w0 = ((A0).x > 0) ? w0 : 0.f; \
    float w1 = ((e0.z >= ethr) ? esti*e0.z : esti2*e0.w); w1 = ((A0).y > 0) ? w1 : 0.f; \
    float w2 = ((e1.x >= ethr) ? esti*e1.x : esti2*e1.y); w2 = ((A0).z > 0) ? w2 : 0.f; \
    float w3 = ((e1.z >= ethr) ? esti*e1.z : esti2*e1.w); w3 = ((A0).w > 0) ? w3 : 0.f; \
    float w4 = ((e2.x >= ethr) ? esti*e2.x : esti2*e2.y); w4 = ((A1).x > 0) ? w4 : 0.f; \
    float w5 = ((e2.z >= ethr) ? esti*e2.z : esti2*e2.w); w5 = ((A1).y > 0) ? w5 : 0.f; \
    float w6 = ((e3.x >= ethr) ? esti*e3.x : esti2*e3.y); w6 = ((A1).z > 0) ? w6 : 0.f; \
    float w7 = ((e3.z >= ethr) ? esti*e3.z : esti2*e3.w); w7 = ((A1).w > 0) ? w7 : 0.f; \
    int p0 = pk2(w0, w1);                                                      \
    int p1 = pk2(w2, w3);                                                      \
    int p2 = pk2(w4, w5);                                                      \
    int p3 = pk2(w6, w7);                                                      \
    dsum += bflo(p0) + bfhi(p0) + bflo(p1) + bfhi(p1)                          \
          + bflo(p2) + bfhi(p2) + bflo(p3) + bfhi(p3);                         \
    int4 ai;                                                                   \
    ai.x = __builtin_amdgcn_ds_bpermute(sidx4, p0);                            \
    ai.y = __builtin_amdgcn_ds_bpermute(sidx4, p1);                            \
    ai.z = __builtin_amdgcn_ds_bpermute(sidx4, p2);                            \
    ai.w = __builtin_amdgcn_ds_bpermute(sidx4, p3);                            \
    short8 afrag = *(short8*)&ai;                                              \
    acc0 = __builtin_amdgcn_mfma_f32_16x16x32_bf16(afrag, b0, acc0, 0, 0, 0);  \
    acc1 = __builtin_amdgcn_mfma_f32_16x16x32_bf16(afrag, b1, acc1, 0, 0, 0);  \
    acc2 = __builtin_amdgcn_mfma_f32_16x16x32_bf16(afrag, b2, acc2, 0, 0, 0);  \
    acc3 = __builtin_amdgcn_mfma_f32_16x16x32_bf16(afrag, b3, acc3, 0, 0, 0);  \
  } while (0)

__launch_bounds__(256, 4)
__global__ void k_attn(const int* __restrict__ adj, float* __restrict__ ws) {
  const float* st = ws + OFF_ST;
  const float* etab = ws + OFF_ETA;
  const unsigned short* hobp = (const unsigned short*)(ws + OFF_HOB);
  float* gnum = ws + OFF_NUM;
  float* gden = ws + OFF_DEN;

  int t = threadIdx.x;
  int wv = t >> 6, lane = t & 63;
  int bx = blockIdx.x;
  int s  = bx & (SPLIT - 1);
  int bi = bx >> 3;                 // log2(SPLIT)
  int i0 = bi * ROWT;
  int jb = s * JSP;

  // source-lane mapping (coalesced loads): row rsrc = lane>>2, chunk csrc = lane&3
  int rsrc = lane >> 2, csrc = lane & 3;
  int irow_s = i0 + wv*16 + rsrc;
  float sti  = st[irow_s];
  float esti  = __expf(sti);
  float esti2 = __expf(0.2f * sti);
  float ethr  = __expf(-sti);

  // adjacency: lane covers j = jb + csrc*8 + tt*32 + e, e=0..7 (2x int4)
  const int* arow = adj + (size_t)irow_s * NO + jb + csrc*8;
  const float* ep = etab + (size_t)(jb + csrc*8) * 2;
  const unsigned short* hpb = hobp + (size_t)(jb >> 5) * 2048 + lane*8;

  // target-lane A-frag mapping + bpermute source index
  int r16 = lane & 15, kg = lane >> 4;
  int sidx4 = ((r16 * 4 + kg) << 2);

  float4v acc0 = (float4v)0.f, acc1 = (float4v)0.f;
  float4v acc2 = (float4v)0.f, acc3 = (float4v)0.f;
  float dsum = 0.f;

  const int NTT = JSP/32;   // 32 tiles
  // prologue: tiles 0 and 1 in flight
  int4v c0a = ntld(arow);           int4v c1a = ntld(arow + 4);
  int4v c0b = ntld(arow + 32);      int4v c1b = ntld(arow + 36);

#pragma unroll 1
  for (int tt = 0; tt < NTT; tt += 2) {
    int t2 = (tt + 2 < NTT) ? tt + 2 : tt;       // clamp: last iter re-loads
    int4v n0a = ntld(arow + t2*32);
    int4v n1a = ntld(arow + t2*32 + 4);
    ATTN_BODY(tt, c0a, c1a);
    int t3 = (tt + 3 < NTT) ? tt + 3 : tt + 1;
    int4v n0b = ntld(arow + t3*32);
    int4v n1b = ntld(arow + t3*32 + 4);
    ATTN_BODY(tt + 1, c0b, c1b);
    c0a = n0a; c1a = n1a; c0b = n0b; c1b = n1b;
  }

  // den: dsum is per (row rsrc, chunk csrc) — reduce over the 4 chunks
  dsum += __shfl_xor(dsum, 1, 64);
  dsum += __shfl_xor(dsum, 2, 64);
  if (csrc == 0) gden[(size_t)s*NT + i0 + wv*16 + rsrc] = dsum;

  // num partials: C/D layout col=lane&15, row=(lane>>4)*4+reg
  size_t obase = ((size_t)s*NT + i0 + wv*16 + kg*4) * FOUT + r16;
#pragma unroll
  for (int r = 0; r < 4; ++r) {
    gnum[obase + (size_t)r*FOUT +  0] = acc0[r];
    gnum[obase + (size_t)r*FOUT + 16] = acc1[r];
    gnum[obase + (size_t)r*FOUT + 32] = acc2[r];
    gnum[obase + (size_t)r*FOUT + 48] = acc3[r];
  }
}

// K_COMB: combine splits, normalize, ELU
__global__ void k_comb(const float* __restrict__ ws, float* __restrict__ out) {
  int idx = blockIdx.x * 256 + threadIdx.x;   // 0..524287
  int i = idx >> 6;
  float num = 0.f, den = 0.f;
#pragma unroll
  for (int s = 0; s < SPLIT; ++s) {
    num += ws[OFF_NUM + ((size_t)s*NT + i)*FOUT + (idx & 63)];
    den += ws[OFF_DEN + (size_t)s*NT + i];
  }
  float r = num / den;
  out[idx] = (r > 0.f) ? r : (__expf(r) - 1.f);
}

extern "C" void kernel_launch(void* const* d_in, const int* in_sizes, int n_in,
                              void* d_out, int out_size, void* d_ws, size_t ws_size,
                              hipStream_t stream) {
  const float* tin = (const float*)d_in[0];
  const float* oin = (const float*)d_in[1];
  const float* Wt  = (const float*)d_in[2];
  const float* Wo  = (const float*)d_in[3];
  const float* a   = (const float*)d_in[4];
  const int*   adj = (const int*)d_in[5];
  float* out = (float*)d_out;
  float* ws  = (float*)d_ws;

  hipLaunchKernelGGL(k_st,   dim3(NT/64),          dim3(256), 0, stream, tin, Wt, a, ws);
  hipLaunchKernelGGL(k_ho,   dim3(NO/16),          dim3(256), 0, stream, oin, Wo, a, ws);
  hipLaunchKernelGGL(k_attn, dim3(NT/ROWT*SPLIT),  dim3(256), 0, stream, adj, ws);
  hipLaunchKernelGGL(k_comb, dim3(NT*FOUT/256),    dim3(256), 0, stream, ws, out);
}